// Round 1
// baseline (224.408 us; speedup 1.0000x reference)
//
#include <hip/hip_runtime.h>

#define BB 16
#define CC 192
#define HH 128
#define WW 128

__global__ __launch_bounds__(256) void geconv_c4_dw_kernel(
    const float* __restrict__ x, const float* __restrict__ wgt, float* __restrict__ out)
{
    const int tx = threadIdx.x;           // 0..31  -> w-vec (4 wide)
    const int ty = threadIdx.y;           // 0..7   -> h within tile
    const int h  = blockIdx.x * 8 + ty;
    const int c  = blockIdx.y;
    const int b  = blockIdx.z;

    // Base 3x3 weights for channel c (block-uniform -> scalar loads)
    float w9[3][3];
#pragma unroll
    for (int i = 0; i < 3; ++i)
#pragma unroll
        for (int j = 0; j < 3; ++j)
            w9[i][j] = wgt[c * 9 + i * 3 + j];

    const int wc = tx * 4;                 // first output col of this thread
    const float* xc = x + ((size_t)b * CC + c) * (HH * WW);

    // 3 rows x 6 cols input patch (cols wc-1 .. wc+4), zero-padded
    float row[3][6];
#pragma unroll
    for (int i = 0; i < 3; ++i) {
        const int hh = h - 1 + i;
        const bool hv = (hh >= 0) && (hh < HH);
        const float* xr = xc + hh * WW;
        float4 mid = hv ? *(const float4*)(xr + wc) : make_float4(0.f, 0.f, 0.f, 0.f);
        row[i][0] = (hv && tx > 0)  ? xr[wc - 1] : 0.f;
        row[i][1] = mid.x;
        row[i][2] = mid.y;
        row[i][3] = mid.z;
        row[i][4] = mid.w;
        row[i][5] = (hv && tx < 31) ? xr[wc + 4] : 0.f;
    }

    // 4 rotations x 4 lanes
    float o[4][4];
#pragma unroll
    for (int k = 0; k < 4; ++k) {
        float s0 = 0.f, s1 = 0.f, s2 = 0.f, s3 = 0.f;
#pragma unroll
        for (int i = 0; i < 3; ++i) {
#pragma unroll
            for (int j = 0; j < 3; ++j) {
                const float v = row[i][k + j];
                s0 = fmaf(v, w9[i][j],         s0);  // r=0: identity
                s1 = fmaf(v, w9[j][2 - i],     s1);  // r=1: rot90
                s2 = fmaf(v, w9[2 - i][2 - j], s2);  // r=2: rot180
                s3 = fmaf(v, w9[2 - j][i],     s3);  // r=3: rot270
            }
        }
        o[0][k] = s0; o[1][k] = s1; o[2][k] = s2; o[3][k] = s3;
    }

    const size_t plane = (size_t)HH * WW;
    size_t outbase = ((size_t)b * (4 * CC) + c) * plane + (size_t)h * WW + wc;
#pragma unroll
    for (int r = 0; r < 4; ++r) {
        float4 v = make_float4(o[r][0], o[r][1], o[r][2], o[r][3]);
        *(float4*)(out + outbase + (size_t)r * CC * plane) = v;
    }
}

extern "C" void kernel_launch(void* const* d_in, const int* in_sizes, int n_in,
                              void* d_out, int out_size, void* d_ws, size_t ws_size,
                              hipStream_t stream) {
    const float* x   = (const float*)d_in[0];
    const float* wgt = (const float*)d_in[1];
    float* out = (float*)d_out;

    dim3 block(32, 8, 1);                 // 256 threads, full 128-wide row strip
    dim3 grid(HH / 8, CC, BB);            // (16, 192, 16)
    geconv_c4_dw_kernel<<<grid, block, 0, stream>>>(x, wgt, out);
}

// Round 3
// 156.530 us; speedup vs baseline: 1.4336x; 1.4336x over previous
//
#include <hip/hip_runtime.h>

#define BB 16
#define CC 192
#define HH 128
#define WW 128
#define ROWS 4   // output rows per thread

typedef float f32x4 __attribute__((ext_vector_type(4)));

__global__ __launch_bounds__(256) void geconv_c4_dw_kernel(
    const float* __restrict__ x, const float* __restrict__ wgt, float* __restrict__ out)
{
    const int tx = threadIdx.x;                       // 0..31 -> w-vec (4 wide)
    const int ty = threadIdx.y;                       // 0..7  -> row-group in block
    const int h0 = blockIdx.x * (8 * ROWS) + ty * ROWS;
    const int c  = blockIdx.y;
    const int b  = blockIdx.z;

    // Base 3x3 weights for channel c (block-uniform)
    float w9[3][3];
#pragma unroll
    for (int i = 0; i < 3; ++i)
#pragma unroll
        for (int j = 0; j < 3; ++j)
            w9[i][j] = wgt[c * 9 + i * 3 + j];

    const int wc = tx * 4;
    const float* xc = x + ((size_t)b * CC + c) * (HH * WW) + wc;

    // Load one padded input row (6 floats: wc-1 .. wc+4) using 1 float4 load
    // + lane shuffles for the horizontal halo (width=32 keeps it within a row).
    auto load_row = [&](int hh, float* r) {
        f32x4 m = {0.f, 0.f, 0.f, 0.f};
        if (hh >= 0 && hh < HH) m = *(const f32x4*)(xc + hh * WW);
        float left  = __shfl_up(m.w, 1, 32);
        float right = __shfl_down(m.x, 1, 32);
        r[0] = (tx == 0)  ? 0.f : left;
        r[1] = m.x; r[2] = m.y; r[3] = m.z; r[4] = m.w;
        r[5] = (tx == 31) ? 0.f : right;
    };

    const size_t plane = (size_t)HH * WW;
    float* ob = out + ((size_t)b * (4 * CC) + c) * plane + (size_t)h0 * WW + wc;

    float r0[6], r1[6], r2[6];
    load_row(h0 - 1, r0);
    load_row(h0,     r1);

#pragma unroll
    for (int rr = 0; rr < ROWS; ++rr) {
        load_row(h0 + rr + 1, r2);

        // 4 rotations x 4 lanes for output row h0+rr
        const float* rows[3] = { r0, r1, r2 };
        float o[4][4];
#pragma unroll
        for (int k = 0; k < 4; ++k) {
            float s0 = 0.f, s1 = 0.f, s2 = 0.f, s3 = 0.f;
#pragma unroll
            for (int i = 0; i < 3; ++i) {
#pragma unroll
                for (int j = 0; j < 3; ++j) {
                    const float v = rows[i][k + j];
                    s0 = fmaf(v, w9[i][j],         s0);  // r=0 identity
                    s1 = fmaf(v, w9[j][2 - i],     s1);  // r=1 rot90
                    s2 = fmaf(v, w9[2 - i][2 - j], s2);  // r=2 rot180
                    s3 = fmaf(v, w9[2 - j][i],     s3);  // r=3 rot270
                }
            }
            o[0][k] = s0; o[1][k] = s1; o[2][k] = s2; o[3][k] = s3;
        }

        float* orow = ob + (size_t)rr * WW;
#pragma unroll
        for (int r = 0; r < 4; ++r) {
            f32x4 v = { o[r][0], o[r][1], o[r][2], o[r][3] };
            __builtin_nontemporal_store(v, (f32x4*)(orow + (size_t)r * CC * plane));
        }

        // roll the window (fully unrolled -> register renaming, no moves)
#pragma unroll
        for (int q = 0; q < 6; ++q) { r0[q] = r1[q]; r1[q] = r2[q]; }
    }
}

extern "C" void kernel_launch(void* const* d_in, const int* in_sizes, int n_in,
                              void* d_out, int out_size, void* d_ws, size_t ws_size,
                              hipStream_t stream) {
    const float* x   = (const float*)d_in[0];
    const float* wgt = (const float*)d_in[1];
    float* out = (float*)d_out;

    dim3 block(32, 8, 1);                   // 256 threads
    dim3 grid(HH / (8 * ROWS), CC, BB);     // (4, 192, 16)
    geconv_c4_dw_kernel<<<grid, block, 0, stream>>>(x, wgt, out);
}